// Round 1
// baseline (1575.198 us; speedup 1.0000x reference)
//
#include <hip/hip_runtime.h>

#define NN 50000
#define NE 800000

// ---------------- degree / normalization ----------------

__global__ void degrees_k(const int* __restrict__ src, const int* __restrict__ dst,
                          float* __restrict__ deg_in, float* __restrict__ deg_out, int E) {
    int e = blockIdx.x * 256 + threadIdx.x;
    if (e < E) {
        atomicAdd(deg_in + dst[e], 1.0f);
        atomicAdd(deg_out + src[e], 1.0f);
    }
}

__global__ void make_inv_k(const float* __restrict__ deg_in, const float* __restrict__ deg_out,
                           float* __restrict__ inv_in, float* __restrict__ inv_out,
                           float* __restrict__ inv_deg_in, int n) {
    int i = blockIdx.x * 256 + threadIdx.x;
    if (i < n) {
        float di = fmaxf(deg_in[i], 1.0f);
        float dq = fmaxf(deg_out[i], 1.0f);
        inv_in[i]     = 1.0f / sqrtf(di);
        inv_out[i]    = 1.0f / sqrtf(dq);
        inv_deg_in[i] = 1.0f / di;
    }
}

// ---------------- edge MLP + scatter-add to dst ----------------
// one thread per (edge, out_feature); 32 out features
__global__ void edge_mlp_scatter_k(const float* __restrict__ ef, const float* __restrict__ We,
                                   const float* __restrict__ be, const int* __restrict__ dst,
                                   float* __restrict__ eacc, int E) {
    int gid = blockIdx.x * 256 + threadIdx.x;
    int e = gid >> 5;
    int f = gid & 31;
    if (e >= E) return;
    const float4* a4 = (const float4*)(ef + (size_t)e * 32);
    float acc = be[f];
#pragma unroll
    for (int i = 0; i < 8; ++i) {
        float4 a = a4[i];
        acc += a.x * We[(4 * i + 0) * 32 + f];
        acc += a.y * We[(4 * i + 1) * 32 + f];
        acc += a.z * We[(4 * i + 2) * 32 + f];
        acc += a.w * We[(4 * i + 3) * 32 + f];
    }
    atomicAdd(eacc + (size_t)dst[e] * 32 + f, acc);
}

// edge_h = relu(eacc / deg_in) into h0[:, 0:32] (stride 128)
__global__ void edge_mean_k(const float* __restrict__ eacc, const float* __restrict__ inv_deg_in,
                            float* __restrict__ h0, int n) {
    int gid = blockIdx.x * 256 + threadIdx.x;
    int node = gid >> 5;
    int f = gid & 31;
    if (node >= n) return;
    float v = eacc[(size_t)node * 32 + f] * inv_deg_in[node];
    h0[(size_t)node * 128 + f] = fmaxf(v, 0.0f);
}

// ---------------- row-block GEMM ----------------
// block = 64 threads (1 wave), TM=16 rows staged in LDS, NOUT features/lane.
// Safe for in==out (stage-then-write, blocks own disjoint rows).
template <int D_IN, int D_OUT, bool RELU, bool SCALE>
__global__ __launch_bounds__(64) void gemm_rows_k(
    const float* __restrict__ in, int in_stride,
    const float* __restrict__ W,       // [D_IN][D_OUT] row-major
    const float* __restrict__ bias,    // [D_OUT]
    const float* __restrict__ scale,   // [rows] or nullptr
    float* __restrict__ out, int out_stride) {
    constexpr int TM = 16;
    constexpr int NOUT = (D_OUT + 63) / 64;
    __shared__ float s_in[TM * D_IN];

    const int row0 = blockIdx.x * TM;
    const int lane = threadIdx.x;

    // stage TM rows (scaled) as float4
    constexpr int NV = TM * D_IN / 4;
    for (int i = lane; i < NV; i += 64) {
        int m = i / (D_IN / 4);
        int kv = i % (D_IN / 4);
        int row = row0 + m;
        float4 v = *(const float4*)(in + (size_t)row * in_stride + kv * 4);
        if (SCALE) {
            float s = scale[row];
            v.x *= s; v.y *= s; v.z *= s; v.w *= s;
        }
        *(float4*)(s_in + m * D_IN + kv * 4) = v;
    }
    __syncthreads();

    int f[NOUT];
    int ff[NOUT];
    bool fok[NOUT];
    float acc[NOUT][TM];
#pragma unroll
    for (int o = 0; o < NOUT; ++o) {
        f[o] = lane + 64 * o;
        fok[o] = (f[o] < D_OUT);
        ff[o] = fok[o] ? f[o] : 0;   // clamp so loads stay in-bounds
        float bv = bias[ff[o]];
#pragma unroll
        for (int m = 0; m < TM; ++m) acc[o][m] = bv;
    }

    for (int k = 0; k < D_IN; k += 4) {
        float w[NOUT][4];
#pragma unroll
        for (int o = 0; o < NOUT; ++o)
#pragma unroll
            for (int j = 0; j < 4; ++j)
                w[o][j] = W[(k + j) * D_OUT + ff[o]];
#pragma unroll
        for (int m = 0; m < TM; ++m) {
            float4 a = *(const float4*)(s_in + m * D_IN + k);
#pragma unroll
            for (int o = 0; o < NOUT; ++o) {
                acc[o][m] += a.x * w[o][0];
                acc[o][m] += a.y * w[o][1];
                acc[o][m] += a.z * w[o][2];
                acc[o][m] += a.w * w[o][3];
            }
        }
    }

#pragma unroll
    for (int o = 0; o < NOUT; ++o) {
        if (!fok[o]) continue;
#pragma unroll
        for (int m = 0; m < TM; ++m) {
            float v = acc[o][m];
            if (RELU) v = fmaxf(v, 0.0f);
            out[(size_t)(row0 + m) * out_stride + f[o]] = v;
        }
    }
}

// ---------------- conv scatter: agg[dst] += h[src] * inv_out[src] ----------------
// block = D threads, 4 edges per block
template <int D>
__global__ __launch_bounds__(D) void scatter_conv_k(
    const float* __restrict__ h, int h_stride,
    const float* __restrict__ inv_out,
    const int* __restrict__ src, const int* __restrict__ dst,
    float* __restrict__ agg, int agg_stride, int E) {
    int e0 = blockIdx.x * 4;
    int fth = threadIdx.x;
#pragma unroll
    for (int i = 0; i < 4; ++i) {
        int e = e0 + i;
        if (e >= E) break;
        int s = src[e];
        int d = dst[e];
        float v = h[(size_t)s * h_stride + fth] * inv_out[s];
        atomicAdd(agg + (size_t)d * agg_stride + fth, v);
    }
}

// ---------------- final 192 -> 2 head ----------------
__global__ void out_layer_k(const float* __restrict__ h, const float* __restrict__ Wo,
                            const float* __restrict__ bo, float* __restrict__ out, int n) {
    int gid = blockIdx.x * 256 + threadIdx.x;
    int node = gid >> 1;
    int c = gid & 1;
    if (node >= n) return;
    const float4* h4 = (const float4*)(h + (size_t)node * 192);
    float acc = bo[c];
#pragma unroll
    for (int i = 0; i < 48; ++i) {
        float4 a = h4[i];
        acc += a.x * Wo[(4 * i + 0) * 2 + c];
        acc += a.y * Wo[(4 * i + 1) * 2 + c];
        acc += a.z * Wo[(4 * i + 2) * 2 + c];
        acc += a.w * Wo[(4 * i + 3) * 2 + c];
    }
    out[(size_t)node * 2 + c] = acc;
}

extern "C" void kernel_launch(void* const* d_in, const int* in_sizes, int n_in,
                              void* d_out, int out_size, void* d_ws, size_t ws_size,
                              hipStream_t stream) {
    const float* node_feats = (const float*)d_in[0];   // [N,64]
    const float* edge_feats = (const float*)d_in[1];   // [E,32]
    const float* Wn  = (const float*)d_in[2];          // [64,96]
    const float* bn  = (const float*)d_in[3];
    const float* We  = (const float*)d_in[4];          // [32,32]
    const float* be  = (const float*)d_in[5];
    const float* Wc0 = (const float*)d_in[6];          // [128,192]
    const float* bc0 = (const float*)d_in[7];
    const float* Wc1 = (const float*)d_in[8];          // [192,192]
    const float* bc1 = (const float*)d_in[9];
    const float* Wl0 = (const float*)d_in[10];         // [192,192]
    const float* bl0 = (const float*)d_in[11];
    const float* Wo  = (const float*)d_in[12];         // [192,2]
    const float* bo  = (const float*)d_in[13];
    const int* src = (const int*)d_in[14];
    const int* dst = (const int*)d_in[15];
    float* out = (float*)d_out;

    const int N = NN, E = NE;
    float* ws = (float*)d_ws;
    // zero-init region (contiguous): deg_in, deg_out, eacc, aggA, aggB
    float* deg_in  = ws;                       // N
    float* deg_out = deg_in + N;               // N
    float* eacc    = deg_out + N;              // 32N
    float* aggA    = eacc + (size_t)32 * N;    // 192N  (also h1 / h3)
    float* aggB    = aggA + (size_t)192 * N;   // 192N  (also h2)
    size_t zero_floats = (size_t)(2 + 32 + 192 + 192) * N;
    float* inv_in     = aggB + (size_t)192 * N;  // N
    float* inv_out    = inv_in + N;              // N
    float* inv_deg_in = inv_out + N;             // N
    float* h0         = inv_deg_in + N;          // 128N

    hipMemsetAsync(d_ws, 0, zero_floats * sizeof(float), stream);

    degrees_k<<<dim3((E + 255) / 256), dim3(256), 0, stream>>>(src, dst, deg_in, deg_out, E);
    make_inv_k<<<dim3((N + 255) / 256), dim3(256), 0, stream>>>(deg_in, deg_out, inv_in, inv_out,
                                                                inv_deg_in, N);

    // edge MLP -> scatter sum on dst
    edge_mlp_scatter_k<<<dim3((E * 32) / 256), dim3(256), 0, stream>>>(edge_feats, We, be, dst,
                                                                       eacc, E);
    // edge_h -> h0[:, 0:32]
    edge_mean_k<<<dim3((N * 32 + 255) / 256), dim3(256), 0, stream>>>(eacc, inv_deg_in, h0, N);
    // node_h -> h0[:, 32:128]
    gemm_rows_k<64, 96, true, false><<<dim3(N / 16), dim3(64), 0, stream>>>(
        node_feats, 64, Wn, bn, nullptr, h0 + 32, 128);

    // conv0: scatter h0 -> aggA (stride 192), then GEMM 128->192 in-place
    scatter_conv_k<128><<<dim3(E / 4), dim3(128), 0, stream>>>(h0, 128, inv_out, src, dst,
                                                               aggA, 192, E);
    gemm_rows_k<128, 192, true, true><<<dim3(N / 16), dim3(64), 0, stream>>>(
        aggA, 192, Wc0, bc0, inv_in, aggA, 192);

    // conv1: scatter aggA(h1) -> aggB, GEMM 192->192 in-place
    scatter_conv_k<192><<<dim3(E / 4), dim3(192), 0, stream>>>(aggA, 192, inv_out, src, dst,
                                                               aggB, 192, E);
    gemm_rows_k<192, 192, true, true><<<dim3(N / 16), dim3(64), 0, stream>>>(
        aggB, 192, Wc1, bc1, inv_in, aggB, 192);

    // linear 192->192: aggB(h2) -> aggA(h3)
    gemm_rows_k<192, 192, true, false><<<dim3(N / 16), dim3(64), 0, stream>>>(
        aggB, 192, Wl0, bl0, nullptr, aggA, 192);

    // head 192->2
    out_layer_k<<<dim3((N * 2 + 255) / 256), dim3(256), 0, stream>>>(aggA, Wo, bo, out, N);
}

// Round 2
// 793.826 us; speedup vs baseline: 1.9843x; 1.9843x over previous
//
#include <hip/hip_runtime.h>

#define NN 50000
#define NE 800000

// ---------------- degrees (int) ----------------
__global__ void degrees_k(const int* __restrict__ src, const int* __restrict__ dst,
                          int* __restrict__ deg_in, int* __restrict__ deg_out, int E) {
    int e = blockIdx.x * 256 + threadIdx.x;
    if (e < E) {
        atomicAdd(deg_in + dst[e], 1);
        atomicAdd(deg_out + src[e], 1);
    }
}

__global__ void make_inv_k(const int* __restrict__ deg_in, const int* __restrict__ deg_out,
                           float* __restrict__ inv_in, float* __restrict__ inv_out,
                           float* __restrict__ inv_mean, float* __restrict__ bcoef, int n) {
    int i = blockIdx.x * 256 + threadIdx.x;
    if (i < n) {
        int d_in = deg_in[i];
        float di = fmaxf((float)d_in, 1.0f);
        float dq = fmaxf((float)deg_out[i], 1.0f);
        inv_in[i]   = 1.0f / sqrtf(di);
        inv_out[i]  = 1.0f / sqrtf(dq);
        inv_mean[i] = 1.0f / di;
        bcoef[i]    = (d_in > 0) ? 1.0f : 0.0f;
    }
}

// ---------------- exclusive scan of deg_in -> row_start ----------------
// chunk = 512 elements per block, 256 threads
__global__ void scan1_k(const int* __restrict__ deg, int* __restrict__ out,
                        int* __restrict__ bsum, int n) {
    __shared__ int ps[256];
    int base = blockIdx.x * 512;
    int t = threadIdx.x;
    int i0 = base + 2 * t, i1 = base + 2 * t + 1;
    int a0 = (i0 < n) ? deg[i0] : 0;
    int a1 = (i1 < n) ? deg[i1] : 0;
    ps[t] = a0 + a1;
    __syncthreads();
    for (int off = 1; off < 256; off <<= 1) {
        int v = (t >= off) ? ps[t - off] : 0;
        __syncthreads();
        ps[t] += v;
        __syncthreads();
    }
    int excl = (t > 0) ? ps[t - 1] : 0;
    if (i0 < n) out[i0] = excl;
    if (i1 < n) out[i1] = excl + a0;
    if (t == 255) bsum[blockIdx.x] = ps[255];
}

__global__ void scan2_k(int* __restrict__ bsum, int nb) {
    __shared__ int s[128];
    int t = threadIdx.x;
    int v = (t < nb) ? bsum[t] : 0;
    s[t] = v;
    __syncthreads();
    for (int off = 1; off < 128; off <<= 1) {
        int u = (t >= off) ? s[t - off] : 0;
        __syncthreads();
        s[t] += u;
        __syncthreads();
    }
    if (t < nb) bsum[t] = s[t] - v;  // exclusive
}

__global__ void scan3_k(int* __restrict__ out, const int* __restrict__ bsum, int n) {
    int i = blockIdx.x * 512 + threadIdx.x * 2;
    int add = bsum[blockIdx.x];
    if (i < n) out[i] += add;
    if (i + 1 < n) out[i + 1] += add;
}

// ---------------- CSR fill ----------------
__global__ void fill_csr_k(const int* __restrict__ src, const int* __restrict__ dst,
                           const int* __restrict__ row_start, int* __restrict__ cursor,
                           int* __restrict__ csr_src, int* __restrict__ csr_eid, int E) {
    int e = blockIdx.x * 256 + threadIdx.x;
    if (e < E) {
        int d = dst[e];
        int p = atomicAdd(cursor + d, 1);
        int idx = row_start[d] + p;
        csr_src[idx] = src[e];
        csr_eid[idx] = e;
    }
}

// ---------------- gather raw edge feats (sum over in-edges) ----------------
// 8 nodes per 256-thread block, 32 feats each
__global__ void gather_edge_k(const float* __restrict__ ef, const int* __restrict__ csr_eid,
                              const int* __restrict__ row_start, const int* __restrict__ deg,
                              float* __restrict__ efa, int n) {
    int node = blockIdx.x * 8 + (threadIdx.x >> 5);
    int f = threadIdx.x & 31;
    if (node >= n) return;
    int beg = row_start[node], cnt = deg[node];
    float acc = 0.0f;
    int i = 0;
    for (; i + 1 < cnt; i += 2) {
        int e0 = csr_eid[beg + i];
        int e1 = csr_eid[beg + i + 1];
        acc += ef[(size_t)e0 * 32 + f];
        acc += ef[(size_t)e1 * 32 + f];
    }
    if (i < cnt) acc += ef[(size_t)csr_eid[beg + i] * 32 + f];
    efa[(size_t)node * 32 + f] = acc;
}

// ---------------- gather conv: agg[d] = sum_e h[src_e]*inv_out[src_e] ----------------
template <int D>
__global__ __launch_bounds__(D) void gather_conv_k(
    const float* __restrict__ h, int h_stride, const float* __restrict__ inv_out,
    const int* __restrict__ csr_src, const int* __restrict__ row_start,
    const int* __restrict__ deg, float* __restrict__ agg, int agg_stride) {
    int node = blockIdx.x;
    int f = threadIdx.x;
    int beg = row_start[node], cnt = deg[node];
    float acc = 0.0f;
    int i = 0;
    for (; i + 1 < cnt; i += 2) {
        int s0 = csr_src[beg + i];
        int s1 = csr_src[beg + i + 1];
        acc += h[(size_t)s0 * h_stride + f] * inv_out[s0];
        acc += h[(size_t)s1 * h_stride + f] * inv_out[s1];
    }
    if (i < cnt) {
        int s0 = csr_src[beg + i];
        acc += h[(size_t)s0 * h_stride + f] * inv_out[s0];
    }
    agg[(size_t)node * agg_stride + f] = acc;
}

// ---------------- row-block GEMM ----------------
// block = 64 threads (1 wave), TM=16 rows staged in LDS, NOUT features/lane.
// Safe for in==out (stage-then-write, blocks own disjoint rows).
template <int D_IN, int D_OUT, bool RELU, bool SCALE, bool BROW>
__global__ __launch_bounds__(64) void gemm_rows_k(
    const float* __restrict__ in, int in_stride,
    const float* __restrict__ W,       // [D_IN][D_OUT] row-major
    const float* __restrict__ bias,    // [D_OUT]
    const float* __restrict__ scale,   // [rows] or nullptr
    const float* __restrict__ brow,    // per-row bias coefficient or nullptr
    float* __restrict__ out, int out_stride) {
    constexpr int TM = 16;
    constexpr int NOUT = (D_OUT + 63) / 64;
    __shared__ float s_in[TM * D_IN];
    __shared__ float s_brow[TM];

    const int row0 = blockIdx.x * TM;
    const int lane = threadIdx.x;

    if (BROW && lane < TM) s_brow[lane] = brow[row0 + lane];

    constexpr int NV = TM * D_IN / 4;
    for (int i = lane; i < NV; i += 64) {
        int m = i / (D_IN / 4);
        int kv = i % (D_IN / 4);
        int row = row0 + m;
        float4 v = *(const float4*)(in + (size_t)row * in_stride + kv * 4);
        if (SCALE) {
            float s = scale[row];
            v.x *= s; v.y *= s; v.z *= s; v.w *= s;
        }
        *(float4*)(s_in + m * D_IN + kv * 4) = v;
    }
    __syncthreads();

    int f[NOUT];
    int ff[NOUT];
    bool fok[NOUT];
    float acc[NOUT][TM];
#pragma unroll
    for (int o = 0; o < NOUT; ++o) {
        f[o] = lane + 64 * o;
        fok[o] = (f[o] < D_OUT);
        ff[o] = fok[o] ? f[o] : 0;
        float bv = bias[ff[o]];
#pragma unroll
        for (int m = 0; m < TM; ++m) acc[o][m] = BROW ? bv * s_brow[m] : bv;
    }

    for (int k = 0; k < D_IN; k += 4) {
        float w[NOUT][4];
#pragma unroll
        for (int o = 0; o < NOUT; ++o)
#pragma unroll
            for (int j = 0; j < 4; ++j)
                w[o][j] = W[(k + j) * D_OUT + ff[o]];
#pragma unroll
        for (int m = 0; m < TM; ++m) {
            float4 a = *(const float4*)(s_in + m * D_IN + k);
#pragma unroll
            for (int o = 0; o < NOUT; ++o) {
                acc[o][m] += a.x * w[o][0];
                acc[o][m] += a.y * w[o][1];
                acc[o][m] += a.z * w[o][2];
                acc[o][m] += a.w * w[o][3];
            }
        }
    }

#pragma unroll
    for (int o = 0; o < NOUT; ++o) {
        if (!fok[o]) continue;
#pragma unroll
        for (int m = 0; m < TM; ++m) {
            float v = acc[o][m];
            if (RELU) v = fmaxf(v, 0.0f);
            out[(size_t)(row0 + m) * out_stride + f[o]] = v;
        }
    }
}

// ---------------- final 192 -> 2 head ----------------
__global__ void out_layer_k(const float* __restrict__ h, const float* __restrict__ Wo,
                            const float* __restrict__ bo, float* __restrict__ out, int n) {
    int gid = blockIdx.x * 256 + threadIdx.x;
    int node = gid >> 1;
    int c = gid & 1;
    if (node >= n) return;
    const float4* h4 = (const float4*)(h + (size_t)node * 192);
    float acc = bo[c];
#pragma unroll
    for (int i = 0; i < 48; ++i) {
        float4 a = h4[i];
        acc += a.x * Wo[(4 * i + 0) * 2 + c];
        acc += a.y * Wo[(4 * i + 1) * 2 + c];
        acc += a.z * Wo[(4 * i + 2) * 2 + c];
        acc += a.w * Wo[(4 * i + 3) * 2 + c];
    }
    out[(size_t)node * 2 + c] = acc;
}

extern "C" void kernel_launch(void* const* d_in, const int* in_sizes, int n_in,
                              void* d_out, int out_size, void* d_ws, size_t ws_size,
                              hipStream_t stream) {
    const float* node_feats = (const float*)d_in[0];   // [N,64]
    const float* edge_feats = (const float*)d_in[1];   // [E,32]
    const float* Wn  = (const float*)d_in[2];          // [64,96]
    const float* bn  = (const float*)d_in[3];
    const float* We  = (const float*)d_in[4];          // [32,32]
    const float* be  = (const float*)d_in[5];
    const float* Wc0 = (const float*)d_in[6];          // [128,192]
    const float* bc0 = (const float*)d_in[7];
    const float* Wc1 = (const float*)d_in[8];          // [192,192]
    const float* bc1 = (const float*)d_in[9];
    const float* Wl0 = (const float*)d_in[10];         // [192,192]
    const float* bl0 = (const float*)d_in[11];
    const float* Wo  = (const float*)d_in[12];         // [192,2]
    const float* bo  = (const float*)d_in[13];
    const int* src = (const int*)d_in[14];
    const int* dst = (const int*)d_in[15];
    float* out = (float*)d_out;

    const int N = NN, E = NE;

    // ---- workspace layout ----
    int* din       = (int*)d_ws;           // N   (zeroed)
    int* dout      = din + N;              // N   (zeroed)
    int* cursor    = dout + N;             // N   (zeroed)
    int* row_start = cursor + N;           // N
    int* bsum      = row_start + N;        // 128
    int* csr_src   = bsum + 128;           // E
    int* csr_eid   = csr_src + E;          // E
    float* inv_in   = (float*)(csr_eid + E);  // N
    float* inv_out  = inv_in + N;             // N
    float* inv_mean = inv_out + N;            // N
    float* bcoef    = inv_mean + N;           // N
    float* efa      = bcoef + N;              // 32N
    float* h0       = efa + (size_t)32 * N;   // 128N
    float* aggA     = h0 + (size_t)128 * N;   // 192N
    float* aggB     = aggA + (size_t)192 * N; // 192N

    hipMemsetAsync(d_ws, 0, (size_t)3 * N * sizeof(int), stream);

    const int nb = (N + 511) / 512;  // 98

    degrees_k<<<dim3((E + 255) / 256), dim3(256), 0, stream>>>(src, dst, din, dout, E);
    make_inv_k<<<dim3((N + 255) / 256), dim3(256), 0, stream>>>(din, dout, inv_in, inv_out,
                                                                inv_mean, bcoef, N);
    scan1_k<<<dim3(nb), dim3(256), 0, stream>>>(din, row_start, bsum, N);
    scan2_k<<<dim3(1), dim3(128), 0, stream>>>(bsum, nb);
    scan3_k<<<dim3(nb), dim3(256), 0, stream>>>(row_start, bsum, N);
    fill_csr_k<<<dim3((E + 255) / 256), dim3(256), 0, stream>>>(src, dst, row_start, cursor,
                                                                csr_src, csr_eid, E);

    // edge aggregation: efa = segment_sum(edge_feats, dst)
    gather_edge_k<<<dim3(N / 8), dim3(256), 0, stream>>>(edge_feats, csr_eid, row_start, din,
                                                         efa, N);
    // h0[:,0:32] = relu((efa/deg)@We + bcoef*be)
    gemm_rows_k<32, 32, true, true, true><<<dim3(N / 16), dim3(64), 0, stream>>>(
        efa, 32, We, be, inv_mean, bcoef, h0, 128);
    // h0[:,32:128] = relu(node_feats@Wn + bn)
    gemm_rows_k<64, 96, true, false, false><<<dim3(N / 16), dim3(64), 0, stream>>>(
        node_feats, 64, Wn, bn, nullptr, nullptr, h0 + 32, 128);

    // conv0: gather h0 -> aggA, then GEMM 128->192 in-place (scale inv_in)
    gather_conv_k<128><<<dim3(N), dim3(128), 0, stream>>>(h0, 128, inv_out, csr_src, row_start,
                                                          din, aggA, 192);
    gemm_rows_k<128, 192, true, true, false><<<dim3(N / 16), dim3(64), 0, stream>>>(
        aggA, 192, Wc0, bc0, inv_in, nullptr, aggA, 192);

    // conv1: gather aggA -> aggB, GEMM 192->192 in-place
    gather_conv_k<192><<<dim3(N), dim3(192), 0, stream>>>(aggA, 192, inv_out, csr_src, row_start,
                                                          din, aggB, 192);
    gemm_rows_k<192, 192, true, true, false><<<dim3(N / 16), dim3(64), 0, stream>>>(
        aggB, 192, Wc1, bc1, inv_in, nullptr, aggB, 192);

    // linear 192->192: aggB -> aggA
    gemm_rows_k<192, 192, true, false, false><<<dim3(N / 16), dim3(64), 0, stream>>>(
        aggB, 192, Wl0, bl0, nullptr, nullptr, aggA, 192);

    // head 192->2
    out_layer_k<<<dim3((N * 2 + 255) / 256), dim3(256), 0, stream>>>(aggA, Wo, bo, out, N);
}

// Round 3
// 716.492 us; speedup vs baseline: 2.1985x; 1.1079x over previous
//
#include <hip/hip_runtime.h>

#define NN 50000
#define NE 800000

// ---------------- degrees (int) ----------------
__global__ void degrees_k(const int* __restrict__ src, const int* __restrict__ dst,
                          int* __restrict__ deg_in, int* __restrict__ deg_out, int E) {
    int e = blockIdx.x * 256 + threadIdx.x;
    if (e < E) {
        atomicAdd(deg_in + dst[e], 1);
        atomicAdd(deg_out + src[e], 1);
    }
}

__global__ void make_inv_k(const int* __restrict__ deg_in, const int* __restrict__ deg_out,
                           float* __restrict__ inv_in, float* __restrict__ inv_out,
                           float* __restrict__ inv_mean, float* __restrict__ bcoef, int n) {
    int i = blockIdx.x * 256 + threadIdx.x;
    if (i < n) {
        int d_in = deg_in[i];
        float di = fmaxf((float)d_in, 1.0f);
        float dq = fmaxf((float)deg_out[i], 1.0f);
        inv_in[i]   = 1.0f / sqrtf(di);
        inv_out[i]  = 1.0f / sqrtf(dq);
        inv_mean[i] = 1.0f / di;
        bcoef[i]    = (d_in > 0) ? 1.0f : 0.0f;
    }
}

// ---------------- exclusive scan of deg_in -> row_start ----------------
__global__ void scan1_k(const int* __restrict__ deg, int* __restrict__ out,
                        int* __restrict__ bsum, int n) {
    __shared__ int ps[256];
    int base = blockIdx.x * 512;
    int t = threadIdx.x;
    int i0 = base + 2 * t, i1 = base + 2 * t + 1;
    int a0 = (i0 < n) ? deg[i0] : 0;
    int a1 = (i1 < n) ? deg[i1] : 0;
    ps[t] = a0 + a1;
    __syncthreads();
    for (int off = 1; off < 256; off <<= 1) {
        int v = (t >= off) ? ps[t - off] : 0;
        __syncthreads();
        ps[t] += v;
        __syncthreads();
    }
    int excl = (t > 0) ? ps[t - 1] : 0;
    if (i0 < n) out[i0] = excl;
    if (i1 < n) out[i1] = excl + a0;
    if (t == 255) bsum[blockIdx.x] = ps[255];
}

__global__ void scan2_k(int* __restrict__ bsum, int nb) {
    __shared__ int s[128];
    int t = threadIdx.x;
    int v = (t < nb) ? bsum[t] : 0;
    s[t] = v;
    __syncthreads();
    for (int off = 1; off < 128; off <<= 1) {
        int u = (t >= off) ? s[t - off] : 0;
        __syncthreads();
        s[t] += u;
        __syncthreads();
    }
    if (t < nb) bsum[t] = s[t] - v;  // exclusive
}

__global__ void scan3_k(int* __restrict__ out, const int* __restrict__ bsum, int n) {
    int i = blockIdx.x * 512 + threadIdx.x * 2;
    int add = bsum[blockIdx.x];
    if (i < n) out[i] += add;
    if (i + 1 < n) out[i + 1] += add;
}

// ---------------- CSR fill ----------------
__global__ void fill_csr_k(const int* __restrict__ src, const int* __restrict__ dst,
                           const int* __restrict__ row_start, int* __restrict__ cursor,
                           int* __restrict__ csr_src, int* __restrict__ csr_eid, int E) {
    int e = blockIdx.x * 256 + threadIdx.x;
    if (e < E) {
        int d = dst[e];
        int p = atomicAdd(cursor + d, 1);
        int idx = row_start[d] + p;
        csr_src[idx] = src[e];
        csr_eid[idx] = e;
    }
}

// ---------------- gather raw edge feats (sum over in-edges) ----------------
// 8 nodes per 256-thread block, 32 feats each
__global__ void gather_edge_k(const float* __restrict__ ef, const int* __restrict__ csr_eid,
                              const int* __restrict__ row_start, const int* __restrict__ deg,
                              float* __restrict__ efa, int n) {
    int node = blockIdx.x * 8 + (threadIdx.x >> 5);
    int f = threadIdx.x & 31;
    if (node >= n) return;
    int beg = row_start[node], cnt = deg[node];
    float acc = 0.0f;
    int i = 0;
    for (; i + 3 < cnt; i += 4) {
        int e0 = csr_eid[beg + i];
        int e1 = csr_eid[beg + i + 1];
        int e2 = csr_eid[beg + i + 2];
        int e3 = csr_eid[beg + i + 3];
        acc += ef[(size_t)e0 * 32 + f];
        acc += ef[(size_t)e1 * 32 + f];
        acc += ef[(size_t)e2 * 32 + f];
        acc += ef[(size_t)e3 * 32 + f];
    }
    for (; i < cnt; ++i) acc += ef[(size_t)csr_eid[beg + i] * 32 + f];
    efa[(size_t)node * 32 + f] = acc;
}

// ---------------- gather conv: agg[d] = sum_e hS[src_e]  (hS pre-scaled by inv_out) --------
template <int D>
__global__ __launch_bounds__(D) void gather_conv_k(
    const float* __restrict__ h, int h_stride,
    const int* __restrict__ csr_src, const int* __restrict__ row_start,
    const int* __restrict__ deg, float* __restrict__ agg, int agg_stride) {
    int node = blockIdx.x;
    int f = threadIdx.x;
    int beg = row_start[node], cnt = deg[node];
    float acc = 0.0f;
    int i = 0;
    for (; i + 3 < cnt; i += 4) {
        int s0 = csr_src[beg + i];
        int s1 = csr_src[beg + i + 1];
        int s2 = csr_src[beg + i + 2];
        int s3 = csr_src[beg + i + 3];
        acc += h[(size_t)s0 * h_stride + f];
        acc += h[(size_t)s1 * h_stride + f];
        acc += h[(size_t)s2 * h_stride + f];
        acc += h[(size_t)s3 * h_stride + f];
    }
    for (; i < cnt; ++i) acc += h[(size_t)csr_src[beg + i] * h_stride + f];
    agg[(size_t)node * agg_stride + f] = acc;
}

// ---------------- column-split GEMM: block = D_OUT threads, 1 out feature/thread ----------
// TM rows staged in LDS (shared by all waves); LDS reads are wave-uniform broadcasts.
// Safe for in==out (block reads only the rows it writes).
template <int D_IN, int D_OUT, int TM, bool RELU, bool SCALE, bool BROW, bool POSTS>
__global__ __launch_bounds__(D_OUT) void gemm_cols_k(
    const float* __restrict__ in, int in_stride,
    const float* __restrict__ W,       // [D_IN][D_OUT] row-major
    const float* __restrict__ bias,    // [D_OUT]
    const float* __restrict__ scale,   // pre-scale per row (inv_in / inv_mean) or nullptr
    const float* __restrict__ brow,    // per-row bias coefficient or nullptr
    const float* __restrict__ posts,   // post-scale per row (inv_out) or nullptr
    float* __restrict__ out, int out_stride) {
    __shared__ float s_in[TM * D_IN];
    __shared__ float s_brow[TM];
    __shared__ float s_posts[TM];

    const int row0 = blockIdx.x * TM;
    const int tid = threadIdx.x;

    if (tid < TM) {
        if (BROW)  s_brow[tid]  = brow[row0 + tid];
        if (POSTS) s_posts[tid] = posts[row0 + tid];
    }

    constexpr int NV = TM * D_IN / 4;
    for (int i = tid; i < NV; i += D_OUT) {
        int m = i / (D_IN / 4);
        int kv = i % (D_IN / 4);
        int row = row0 + m;
        float4 v = *(const float4*)(in + (size_t)row * in_stride + kv * 4);
        if (SCALE) {
            float s = scale[row];
            v.x *= s; v.y *= s; v.z *= s; v.w *= s;
        }
        *(float4*)(s_in + m * D_IN + kv * 4) = v;
    }
    __syncthreads();

    float acc[TM];
    {
        float bv = bias[tid];
#pragma unroll
        for (int m = 0; m < TM; ++m) acc[m] = BROW ? bv * s_brow[m] : bv;
    }

    for (int k = 0; k < D_IN; k += 8) {
        float w[8];
#pragma unroll
        for (int j = 0; j < 8; ++j) w[j] = W[(k + j) * D_OUT + tid];
#pragma unroll
        for (int m = 0; m < TM; ++m) {
            float4 a0 = *(const float4*)(s_in + m * D_IN + k);
            float4 a1 = *(const float4*)(s_in + m * D_IN + k + 4);
            acc[m] = fmaf(a0.x, w[0], acc[m]);
            acc[m] = fmaf(a0.y, w[1], acc[m]);
            acc[m] = fmaf(a0.z, w[2], acc[m]);
            acc[m] = fmaf(a0.w, w[3], acc[m]);
            acc[m] = fmaf(a1.x, w[4], acc[m]);
            acc[m] = fmaf(a1.y, w[5], acc[m]);
            acc[m] = fmaf(a1.z, w[6], acc[m]);
            acc[m] = fmaf(a1.w, w[7], acc[m]);
        }
    }

#pragma unroll
    for (int m = 0; m < TM; ++m) {
        float v = acc[m];
        if (RELU) v = fmaxf(v, 0.0f);
        if (POSTS) v *= s_posts[m];
        out[(size_t)(row0 + m) * out_stride + tid] = v;
    }
}

// ---------------- final 192 -> 2 head ----------------
__global__ void out_layer_k(const float* __restrict__ h, const float* __restrict__ Wo,
                            const float* __restrict__ bo, float* __restrict__ out, int n) {
    int gid = blockIdx.x * 256 + threadIdx.x;
    int node = gid >> 1;
    int c = gid & 1;
    if (node >= n) return;
    const float4* h4 = (const float4*)(h + (size_t)node * 192);
    float acc = bo[c];
#pragma unroll
    for (int i = 0; i < 48; ++i) {
        float4 a = h4[i];
        acc += a.x * Wo[(4 * i + 0) * 2 + c];
        acc += a.y * Wo[(4 * i + 1) * 2 + c];
        acc += a.z * Wo[(4 * i + 2) * 2 + c];
        acc += a.w * Wo[(4 * i + 3) * 2 + c];
    }
    out[(size_t)node * 2 + c] = acc;
}

extern "C" void kernel_launch(void* const* d_in, const int* in_sizes, int n_in,
                              void* d_out, int out_size, void* d_ws, size_t ws_size,
                              hipStream_t stream) {
    const float* node_feats = (const float*)d_in[0];   // [N,64]
    const float* edge_feats = (const float*)d_in[1];   // [E,32]
    const float* Wn  = (const float*)d_in[2];          // [64,96]
    const float* bn  = (const float*)d_in[3];
    const float* We  = (const float*)d_in[4];          // [32,32]
    const float* be  = (const float*)d_in[5];
    const float* Wc0 = (const float*)d_in[6];          // [128,192]
    const float* bc0 = (const float*)d_in[7];
    const float* Wc1 = (const float*)d_in[8];          // [192,192]
    const float* bc1 = (const float*)d_in[9];
    const float* Wl0 = (const float*)d_in[10];         // [192,192]
    const float* bl0 = (const float*)d_in[11];
    const float* Wo  = (const float*)d_in[12];         // [192,2]
    const float* bo  = (const float*)d_in[13];
    const int* src = (const int*)d_in[14];
    const int* dst = (const int*)d_in[15];
    float* out = (float*)d_out;

    const int N = NN, E = NE;

    // ---- workspace layout ----
    int* din       = (int*)d_ws;           // N   (zeroed)
    int* dout      = din + N;              // N   (zeroed)
    int* cursor    = dout + N;             // N   (zeroed)
    int* row_start = cursor + N;           // N
    int* bsum      = row_start + N;        // 128
    int* csr_src   = bsum + 128;           // E
    int* csr_eid   = csr_src + E;          // E
    float* inv_in   = (float*)(csr_eid + E);  // N
    float* inv_out  = inv_in + N;             // N
    float* inv_mean = inv_out + N;            // N
    float* bcoef    = inv_mean + N;           // N
    float* efa      = bcoef + N;              // 32N
    float* h0       = efa + (size_t)32 * N;   // 128N  (pre-scaled by inv_out)
    float* aggA     = h0 + (size_t)128 * N;   // 192N
    float* aggB     = aggA + (size_t)192 * N; // 192N

    hipMemsetAsync(d_ws, 0, (size_t)3 * N * sizeof(int), stream);

    const int nb = (N + 511) / 512;  // 98

    degrees_k<<<dim3((E + 255) / 256), dim3(256), 0, stream>>>(src, dst, din, dout, E);
    make_inv_k<<<dim3((N + 255) / 256), dim3(256), 0, stream>>>(din, dout, inv_in, inv_out,
                                                                inv_mean, bcoef, N);
    scan1_k<<<dim3(nb), dim3(256), 0, stream>>>(din, row_start, bsum, N);
    scan2_k<<<dim3(1), dim3(128), 0, stream>>>(bsum, nb);
    scan3_k<<<dim3(nb), dim3(256), 0, stream>>>(row_start, bsum, N);
    fill_csr_k<<<dim3((E + 255) / 256), dim3(256), 0, stream>>>(src, dst, row_start, cursor,
                                                                csr_src, csr_eid, E);

    // edge aggregation: efa = segment_sum(edge_feats, dst)
    gather_edge_k<<<dim3(N / 8), dim3(256), 0, stream>>>(edge_feats, csr_eid, row_start, din,
                                                         efa, N);
    // h0[:,0:32] = relu((efa/deg)@We + bcoef*be) * inv_out
    gemm_cols_k<32, 32, 16, true, true, true, true><<<dim3(N / 16), dim3(32), 0, stream>>>(
        efa, 32, We, be, inv_mean, bcoef, inv_out, h0, 128);
    // h0[:,32:128] = relu(node_feats@Wn + bn) * inv_out
    gemm_cols_k<64, 96, 16, true, false, false, true><<<dim3(N / 16), dim3(96), 0, stream>>>(
        node_feats, 64, Wn, bn, nullptr, nullptr, inv_out, h0 + 32, 128);

    // conv0: gather h0 -> aggA, then GEMM 128->192 in-place; post-scale inv_out for conv1
    gather_conv_k<128><<<dim3(N), dim3(128), 0, stream>>>(h0, 128, csr_src, row_start,
                                                          din, aggA, 192);
    gemm_cols_k<128, 192, 16, true, true, false, true><<<dim3(N / 16), dim3(192), 0, stream>>>(
        aggA, 192, Wc0, bc0, inv_in, nullptr, inv_out, aggA, 192);

    // conv1: gather aggA -> aggB, GEMM 192->192 in-place (no post-scale)
    gather_conv_k<192><<<dim3(N), dim3(192), 0, stream>>>(aggA, 192, csr_src, row_start,
                                                          din, aggB, 192);
    gemm_cols_k<192, 192, 16, true, true, false, false><<<dim3(N / 16), dim3(192), 0, stream>>>(
        aggB, 192, Wc1, bc1, inv_in, nullptr, nullptr, aggB, 192);

    // linear 192->192: aggB -> aggA
    gemm_cols_k<192, 192, 16, true, false, false, false><<<dim3(N / 16), dim3(192), 0, stream>>>(
        aggB, 192, Wl0, bl0, nullptr, nullptr, nullptr, aggA, 192);

    // head 192->2
    out_layer_k<<<dim3((N * 2 + 255) / 256), dim3(256), 0, stream>>>(aggA, Wo, bo, out, N);
}